// Round 9
// baseline (510.569 us; speedup 1.0000x reference)
//
#include <hip/hip_runtime.h>

// HGNN layer, v22 — fp32. v21 pipeline (351.6µs proven) with two changes:
// (1) count m-vectorization float4 -> float8 per thread: per c-iteration
//     1 LDS b128 + 2 adjacent 16B global loads + 32 FMA (was 1+1+16).
//     Accumulation per (p,m) stays c-ascending scalar -> bit-identical keys.
// (2) select: bisection (kth, ~31 serial rounds/row) replaced by the pop
//     machinery with runtime kk (avg 11 pops) — same (key,m)-lex emission
//     order, identical pairs/indeg output.
// B=4, N=2304, C=64.

#define HB    4
#define HN    2304
#define HC    64
#define HK    11             // K_NEIGS + 1
#define HL    48
#define HW    22             // windows per dim
#define HE2   484            // 22*22 local edges
#define HE    (HN + HE2)
#define HRPB  4              // rows per block == waves per block
#define NSLOT 36             // keys per lane (2304/64)
#define NPAIRS (HB * HK * HN)   // sum of Dv == 11*N per batch, exact

__global__ void hg14_sentinel(float* out, int n) {
    int i = blockIdx.x * 256 + threadIdx.x;
    if (i < n) out[i] = 12345.0f;
}

__global__ void hg14_init(int* Dv, int* indeg, float* bnsum, float* bnss) {
    int i = blockIdx.x * 256 + threadIdx.x;
    if (i < HB * HN) { Dv[i] = 0; indeg[i] = 0; }
    if (i < HC) { bnsum[i] = 0.f; bnss[i] = 0.f; }
}

// -------- linear h1 = x W^T + b, xsq, f32 transpose -----------------------
__global__ __launch_bounds__(64) void hg14_linear(const float* x, const float* W,
                                                  const float* bias, float* h1,
                                                  float* xsq, float* xT) {
    int row = blockIdx.x;            // 0..B*N-1
    int t = threadIdx.x;
    __shared__ float xr[HC];
    float v = x[row * HC + t];
    xr[t] = v;
    __syncthreads();
    float sq = v * v;
    #pragma unroll
    for (int o = 32; o > 0; o >>= 1) sq += __shfl_xor(sq, o);
    if (t == 0) xsq[row] = sq;
    int b = row / HN, n = row % HN;
    xT[(b * HC + t) * HN + n] = v;
    float acc = bias[t];
    #pragma unroll 8
    for (int c = 0; c < HC; c++) acc += xr[c] * W[t * HC + c];
    h1[row * HC + t] = acc;
}

// ======== pop machinery (v12-proven) ======================================
__device__ __forceinline__ unsigned hg14_wave_min_u32(unsigned v) {
    #pragma unroll
    for (int o = 32; o > 0; o >>= 1) {
        unsigned ov = __shfl_xor(v, o);
        v = ov < v ? ov : v;
    }
    return v;
}

#define HG14_INS4(q0, q1, q2, q3, x)                                     \
    {                                                                    \
        unsigned long long x_ = (x), n_;                                 \
        n_ = q0 < x_ ? q0 : x_; x_ = q0 < x_ ? x_ : q0; q0 = n_;         \
        n_ = q1 < x_ ? q1 : x_; x_ = q1 < x_ ? x_ : q1; q1 = n_;         \
        n_ = q2 < x_ ? q2 : x_; x_ = q2 < x_ ? x_ : q2; q2 = n_;         \
        if (x_ < q3) q3 = x_;                                            \
    }

#define HG14_CE(u, v)                                                    \
    { unsigned long long t_ = u < v ? u : v; v = u < v ? v : u; u = t_; }

#define HG14_BUILD()                                                               \
    {                                                                              \
        unsigned long long a0 = CINF, a1 = CINF, a2 = CINF, a3 = CINF;             \
        unsigned long long b0 = CINF, b1 = CINF, b2 = CINF, b3 = CINF;             \
        _Pragma("unroll")                                                          \
        for (int s = 0; s < NSLOT / 2; s++) {                                      \
            unsigned long long pa = ((unsigned long long)key[s] << 12) |           \
                                    (unsigned)((s << 6) | lane);                   \
            unsigned long long pb = ((unsigned long long)key[s + 18] << 12) |      \
                                    (unsigned)(((s + 18) << 6) | lane);            \
            HG14_INS4(a0, a1, a2, a3, pa);                                         \
            HG14_INS4(b0, b1, b2, b3, pb);                                         \
        }                                                                          \
        c0 = a0 < b3 ? a0 : b3; c1 = a1 < b2 ? a1 : b2;                            \
        c2 = a2 < b1 ? a2 : b1; c3 = a3 < b0 ? a3 : b0;                            \
        HG14_CE(c0, c2); HG14_CE(c1, c3); HG14_CE(c0, c1); HG14_CE(c2, c3);        \
    }

#define HG14_EXTRACT(kk, EMIT)                                                     \
    {                                                                              \
        for (int j = 0; j < (kk); j++) {                                           \
            unsigned hk = (unsigned)(c0 >> 12);                                    \
            unsigned mk = hg14_wave_min_u32(hk);                                   \
            unsigned long long bal = __ballot(hk == mk);                           \
            bool iswin;                                                            \
            if (__popcll(bal) == 1) {                                              \
                iswin = (hk == mk);                                                \
            } else {                                                               \
                unsigned mc = (hk == mk) ? (unsigned)(c0 & 0xFFFu) : 0xFFFFFFFFu;  \
                unsigned mm = hg14_wave_min_u32(mc);                               \
                iswin = (mc == mm);                                                \
            }                                                                      \
            if (iswin) {                                                           \
                int bi = (int)(c0 & 0xFFFu);                                       \
                EMIT;                                                              \
                unsigned long long popped = c0;                                    \
                c0 = c1; c1 = c2; c2 = c3; c3 = CINF;                              \
                if (c0 == CINF) {                                                  \
                    _Pragma("unroll")                                              \
                    for (int s = 0; s < NSLOT; s++) {                              \
                        unsigned long long pk =                                    \
                            ((unsigned long long)key[s] << 12) |                   \
                            (unsigned)((s << 6) | lane);                           \
                        if (pk > popped) HG14_INS4(c0, c1, c2, c3, pk);            \
                    }                                                              \
                }                                                                  \
            }                                                                      \
        }                                                                          \
    }

// ======== bisection machinery (v13-proven): fallback select only ==========
__device__ __forceinline__ void hg14_kth(const unsigned (&key)[NSLOT], int kk,
                                         unsigned& T, int& cntLess, int& take) {
    unsigned andv = 0xFFFFFFFFu, orv = 0u;
    #pragma unroll
    for (int s = 0; s < NSLOT; s++) { andv &= key[s]; orv |= key[s]; }
    #pragma unroll
    for (int o = 32; o > 0; o >>= 1) {
        andv &= (unsigned)__shfl_xor((int)andv, o);
        orv  |= (unsigned)__shfl_xor((int)orv, o);
    }
    unsigned diff = andv ^ orv;
    if (diff == 0u) { T = andv; cntLess = 0; take = kk; return; }
    int tstart = 31 - __builtin_clz(diff);
    unsigned lowmask = (tstart == 31) ? 0xFFFFFFFFu : ((1u << (tstart + 1)) - 1u);
    unsigned pref = andv & ~lowmask;
    int r = kk;
    for (int t = tstart; t >= 0; t--) {
        unsigned pt = pref >> t;
        int c = 0;
        #pragma unroll
        for (int s = 0; s < NSLOT; s++) c += ((key[s] >> t) == pt) ? 1 : 0;
        #pragma unroll
        for (int o = 32; o > 0; o >>= 1) c += __shfl_xor(c, o);
        if (r > c) { r -= c; pref |= (1u << t); }
    }
    T = pref; cntLess = kk - r; take = r;
}

__device__ __forceinline__ void hg14_scan64(int v, int lane, int& excl, int& total) {
    int inc = v;
    #pragma unroll
    for (int o = 1; o < 64; o <<= 1) {
        int u = __shfl_up(inc, o);
        if (lane >= o) inc += u;
    }
    excl = inc - v;
    total = __shfl(inc, 63);
}

// -------- kNN count v22: float8 m-vectorization + key store + pop top-11 --
#define HG22_R(qa, qb, s)                                                \
    qa.x += (s) * u.x; qa.y += (s) * u.y; qa.z += (s) * u.z; qa.w += (s) * u.w; \
    qb.x += (s) * v.x; qb.y += (s) * v.y; qb.z += (s) * v.z; qb.w += (s) * v.w;

#define HG22_ST(row, qa, qb, mm)                                               \
    *reinterpret_cast<float4*>(&d[row][(mm)]) =                                \
        make_float4(xs[row] + s0.x - 2.f * qa.x, xs[row] + s0.y - 2.f * qa.y,  \
                    xs[row] + s0.z - 2.f * qa.z, xs[row] + s0.w - 2.f * qa.w); \
    *reinterpret_cast<float4*>(&d[row][(mm) + 4]) =                            \
        make_float4(xs[row] + s1.x - 2.f * qb.x, xs[row] + s1.y - 2.f * qb.y,  \
                    xs[row] + s1.z - 2.f * qb.z, xs[row] + s1.w - 2.f * qb.w);

#define HG22_DIST8(mm)                                                         \
    {                                                                          \
        float4 q0a = {0.f,0.f,0.f,0.f}, q0b = {0.f,0.f,0.f,0.f};               \
        float4 q1a = {0.f,0.f,0.f,0.f}, q1b = {0.f,0.f,0.f,0.f};               \
        float4 q2a = {0.f,0.f,0.f,0.f}, q2b = {0.f,0.f,0.f,0.f};               \
        float4 q3a = {0.f,0.f,0.f,0.f}, q3b = {0.f,0.f,0.f,0.f};               \
        _Pragma("unroll 8")                                                    \
        for (int c = 0; c < HC; c++) {                                         \
            float4 xq = *reinterpret_cast<const float4*>(&xrt[c][0]);          \
            const float* bp = &xT[(b * HC + c) * HN + (mm)];                   \
            float4 u = *reinterpret_cast<const float4*>(bp);                   \
            float4 v = *reinterpret_cast<const float4*>(bp + 4);               \
            HG22_R(q0a, q0b, xq.x); HG22_R(q1a, q1b, xq.y);                    \
            HG22_R(q2a, q2b, xq.z); HG22_R(q3a, q3b, xq.w);                    \
        }                                                                      \
        float4 s0 = *reinterpret_cast<const float4*>(&xsq[b * HN + (mm)]);     \
        float4 s1 = *reinterpret_cast<const float4*>(&xsq[b * HN + (mm) + 4]); \
        HG22_ST(0, q0a, q0b, (mm)); HG22_ST(1, q1a, q1b, (mm));                \
        HG22_ST(2, q2a, q2b, (mm)); HG22_ST(3, q3a, q3b, (mm));                \
    }

__global__ __launch_bounds__(256) void hg22_knn_count(const float* xT, const float* xsq,
                                                      int* Dv, unsigned int* kcache,
                                                      int storekeys) {
    __shared__ float d[HRPB][HN];                // 36 KB
    __shared__ __align__(16) float xrt[HC][HRPB];// [c][row] -> b128 uniform reads
    const int t = threadIdx.x;
    const int b = blockIdx.x / (HN / HRPB);
    const int n0 = (blockIdx.x % (HN / HRPB)) * HRPB;
    const int r = t >> 6;
    const int lane = t & 63;
    xrt[lane][r] = xT[(b * HC + lane) * HN + n0 + r];
    __syncthreads();
    float xs[HRPB];
    #pragma unroll
    for (int q = 0; q < HRPB; q++) xs[q] = xsq[b * HN + n0 + q];

    // per-(p,m) accumulation stays c-ascending scalar fp: bit-identical
    HG22_DIST8(8 * t);                           // m = 0..2047
    if (t < 32) HG22_DIST8(2048 + 8 * t);        // tail m = 2048..2303
    __syncthreads();

    const int p = n0 + r;
    const unsigned long long CINF = ~0ull;
    unsigned int key[NSLOT];
    unsigned long long c0, c1, c2, c3;
    const int rowbase = (b * HN + p) * NSLOT;
    #pragma unroll
    for (int s = 0; s < NSLOT; s++) {
        float f = d[r][(s << 6) | lane];
        unsigned int ub = __float_as_uint(f);
        unsigned int k = ub ^ (((unsigned int)(((int)ub) >> 31)) | 0x80000000u);
        key[s] = k;
        if (storekeys) kcache[(rowbase + s) * 64 + lane] = k;
    }
    HG14_BUILD();
    HG14_EXTRACT(HK, atomicAdd(&Dv[b * HN + bi], 1));
}

// -------- exclusive scan of Dv (9216 = 256*36) into offs, wave-parallel ---
__global__ __launch_bounds__(256) void hg15_scan(const int* Dv, int* offs) {
    __shared__ int wsum[4];
    int t = threadIdx.x;
    int lane = t & 63, w = t >> 6;
    int base = t * 36;
    int s = 0;
    for (int i = 0; i < 36; i++) s += max(Dv[base + i], 1);
    int inc = s;
    #pragma unroll
    for (int o = 1; o < 64; o <<= 1) {
        int u = __shfl_up(inc, o);
        if (lane >= o) inc += u;
    }
    if (lane == 63) wsum[w] = inc;
    __syncthreads();
    int woff = 0;
    for (int i = 0; i < w; i++) woff += wsum[i];
    int acc = woff + inc - s;                    // exclusive prefix for this thread
    for (int i = 0; i < 36; i++) { offs[base + i] = acc; acc += max(Dv[base + i], 1); }
}

// -------- kNN select v22: cached keys + pop emission (runtime kk) ---------
__global__ __launch_bounds__(256) void hg22_sel(const unsigned int* kcache,
                                                const int* Dv, const int* offs,
                                                int* indeg, unsigned int* pairs) {
    const int t = threadIdx.x;
    const int lane = t & 63;
    const int gw = blockIdx.x * HRPB + (t >> 6);   // global row 0..B*N-1
    const int b = gw / HN, p = gw % HN;
    unsigned int key[NSLOT];
    const int rowbase = gw * NSLOT;
    #pragma unroll
    for (int s = 0; s < NSLOT; s++) key[s] = kcache[(rowbase + s) * 64 + lane];
    const int kk = max(Dv[gw], 1);               // wave-uniform
    const int base = offs[gw];
    const unsigned long long CINF = ~0ull;
    unsigned long long c0, c1, c2, c3;
    HG14_BUILD();
    HG14_EXTRACT(kk,
        { atomicAdd(&indeg[b * HN + bi], 1);
          pairs[base + j] = ((unsigned)b << 24) | ((unsigned)p << 12) | (unsigned)bi; });
}

// -------- select body (v13-proven), fallback path only --------------------
__device__ __forceinline__ void hg14_select_emit(const unsigned (&key)[NSLOT],
                                                 int b, int p, int lane, int kk, int base,
                                                 int* indeg, unsigned int* pairs) {
    unsigned T; int cntLess, take;
    hg14_kth(key, kk, T, cntLess, take);
    int cl = 0;
    #pragma unroll
    for (int s = 0; s < NSLOT; s++) cl += (key[s] < T) ? 1 : 0;
    int off, tot;
    hg14_scan64(cl, lane, off, tot);
    int w = 0;
    #pragma unroll
    for (int s = 0; s < NSLOT; s++) {
        if (key[s] < T) {
            int m = (s << 6) | lane;
            atomicAdd(&indeg[b * HN + m], 1);
            pairs[base + off + w] =
                ((unsigned)b << 24) | ((unsigned)p << 12) | (unsigned)m;
            w++;
        }
    }
    int lastm = -1;
    for (int t2 = 0; t2 < take; t2++) {
        int mc = 0x7FFFFFFF;
        #pragma unroll
        for (int s = 0; s < NSLOT; s++) {
            int m = (s << 6) | lane;
            if (key[s] == T && m > lastm && m < mc) mc = m;
        }
        int mmin = mc;
        #pragma unroll
        for (int o = 32; o > 0; o >>= 1) {
            int ov = __shfl_xor(mmin, o);
            mmin = ov < mmin ? ov : mmin;
        }
        if (mc == mmin) {
            atomicAdd(&indeg[b * HN + mmin], 1);
            pairs[base + cntLess + t2] =
                ((unsigned)b << 24) | ((unsigned)p << 12) | (unsigned)mmin;
        }
        lastm = mmin;
    }
}

// -------- kNN select, full recompute (fallback, no kcache ws) -------------
__global__ __launch_bounds__(256) void hg14_knn_sel_full(const float* xT, const float* xsq,
                                                         const int* Dv, const int* offs,
                                                         int* indeg, unsigned int* pairs) {
    __shared__ float d[HRPB][HN];
    __shared__ float xr[HRPB][HC];
    const int t = threadIdx.x;
    const int b = blockIdx.x / (HN / HRPB);
    const int n0 = (blockIdx.x % (HN / HRPB)) * HRPB;
    const int r = t >> 6;
    const int lane = t & 63;
    xr[r][lane] = xT[(b * HC + lane) * HN + n0 + r];
    __syncthreads();
    float xs[HRPB];
    #pragma unroll
    for (int q = 0; q < HRPB; q++) xs[q] = xsq[b * HN + n0 + q];
    for (int m = t; m < HN; m += 256) {
        float dot0 = 0.f, dot1 = 0.f, dot2 = 0.f, dot3 = 0.f;
        #pragma unroll 8
        for (int c = 0; c < HC; c++) {
            float xv = xT[(b * HC + c) * HN + m];
            dot0 += xr[0][c] * xv;
            dot1 += xr[1][c] * xv;
            dot2 += xr[2][c] * xv;
            dot3 += xr[3][c] * xv;
        }
        float xsm = xsq[b * HN + m];
        d[0][m] = xs[0] + xsm - 2.f * dot0;
        d[1][m] = xs[1] + xsm - 2.f * dot1;
        d[2][m] = xs[2] + xsm - 2.f * dot2;
        d[3][m] = xs[3] + xsm - 2.f * dot3;
    }
    __syncthreads();
    const int p = n0 + r;
    unsigned int key[NSLOT];
    #pragma unroll
    for (int s = 0; s < NSLOT; s++) {
        float f = d[r][(s << 6) | lane];
        unsigned int ub = __float_as_uint(f);
        key[s] = ub ^ (((unsigned int)(((int)ub) >> 31)) | 0x80000000u);
    }
    const int gw = b * HN + p;
    hg14_select_emit(key, b, p, lane, max(Dv[gw], 1), offs[gw], indeg, pairs);
}

__device__ __forceinline__ int hg14_lo(int rc) { return max(0, (rc - 3) / 2); }
__device__ __forceinline__ int hg14_hi(int rc) { return min(HW - 1, rc / 2); }

// -------- y = Dv^-1/2 * h1 (in place) -------------------------------------
__global__ __launch_bounds__(256) void hg14_scale(float* h1, const int* indeg) {
    int i = blockIdx.x * 256 + threadIdx.x;
    int node = i >> 6;
    int n = node % HN;
    int r = n / HL, c = n % HL;
    int cover = max(0, hg14_hi(r) - hg14_lo(r) + 1) * max(0, hg14_hi(c) - hg14_lo(c) + 1);
    int dvn = max(indeg[node] + cover, 1);
    h1[i] *= rsqrtf((float)dvn);
}

// -------- zero z (kNN-edge part) and h2 -----------------------------------
__global__ void hg14_zero(float* z, float* h2) {
    int i = blockIdx.x * 256 + threadIdx.x;      // over B*N*C
    int b = i / (HN * HC), rem = i % (HN * HC);
    z[b * HE * HC + rem] = 0.f;
    h2[i] = 0.f;
}

// -------- fused edge kernel: kNN scatter + window means -------------------
__global__ __launch_bounds__(256) void hg14_edge(const unsigned int* pairs, const int* Dv,
                                                 const float* y, float* z) {
    int wv = (blockIdx.x * 256 + threadIdx.x) >> 6;
    int lane = threadIdx.x & 63;
    if (wv < NPAIRS) {
        unsigned int pk = pairs[wv];
        int b = pk >> 24;
        if (b >= HB) return;                     // defensive (poison)
        int p = (pk >> 12) & 0xFFF, m = pk & 0xFFF;
        float invde = 1.f / (float)max(Dv[b * HN + p], 1);
        atomicAdd(&z[(b * HE + p) * HC + lane], y[(b * HN + m) * HC + lane] * invde);
    } else {
        int w2 = wv - NPAIRS;
        if (w2 >= HB * HE2) return;
        int b = w2 / HE2, w = w2 % HE2;
        int wr = w / HW, wc = w % HW;
        float acc = 0.f;
        #pragma unroll
        for (int i = 0; i < 5; i++)
            #pragma unroll
            for (int j = 0; j < 5; j++)
                acc += y[(b * HN + (wr * 2 + i) * HL + wc * 2 + j) * HC + lane];
        z[(b * HE + HN + w) * HC + lane] = acc * (1.f / 25.f);
    }
}

// -------- h2[m] += z[p] over the pair list (atomic) -----------------------
__global__ __launch_bounds__(256) void hg14_gscatter(const unsigned int* pairs,
                                                     const float* z, float* h2) {
    int idx = (blockIdx.x * 256 + threadIdx.x) >> 6;
    int lane = threadIdx.x & 63;
    if (idx >= NPAIRS) return;
    unsigned int pk = pairs[idx];
    int b = pk >> 24;
    if (b >= HB) return;                         // defensive (poison)
    int p = (pk >> 12) & 0xFFF, m = pk & 0xFFF;
    atomicAdd(&h2[(b * HN + m) * HC + lane], z[(b * HE + p) * HC + lane]);
}

// -------- add window contributions + final Dv^-1/2 scale ------------------
__global__ __launch_bounds__(256) void hg14_gfinish(const float* z, const int* indeg, float* h2) {
    int wave = (blockIdx.x * 256 + threadIdx.x) >> 6;  // one wave per (b, node)
    int lane = threadIdx.x & 63;
    int b = wave / HN, n = wave % HN;
    int g = b * HN + n;
    float acc = h2[g * HC + lane];
    int r = n / HL, c = n % HL;
    int rlo = hg14_lo(r), rhi = hg14_hi(r), clo = hg14_lo(c), chi = hg14_hi(c);
    for (int wr = rlo; wr <= rhi; wr++)
        for (int wc = clo; wc <= chi; wc++)
            acc += z[(b * HE + HN + wr * HW + wc) * HC + lane];
    int dvn = max(indeg[g] + max(0, rhi - rlo + 1) * max(0, chi - clo + 1), 1);
    h2[g * HC + lane] = acc * rsqrtf((float)dvn);
}

// -------- BN stats --------------------------------------------------------
__global__ __launch_bounds__(256) void hg14_bnstats(const float* h2, float* bnsum, float* bnss) {
    int t = threadIdx.x;
    int c = t & 63, rg = t >> 6;
    int row0 = blockIdx.x * 36;      // 256 blocks * 36 rows = 9216
    float s = 0.f, ss = 0.f;
    for (int r = rg; r < 36; r += 4) {
        float v = h2[(row0 + r) * HC + c];
        s += v; ss += v * v;
    }
    __shared__ float ls[256], lss[256];
    ls[t] = s; lss[t] = ss;
    __syncthreads();
    if (t < 64) {
        s  = ls[t]  + ls[t + 64]  + ls[t + 128]  + ls[t + 192];
        ss = lss[t] + lss[t + 64] + lss[t + 128] + lss[t + 192];
        atomicAdd(&bnsum[t], s);
        atomicAdd(&bnss[t], ss);
    }
}

// -------- BN + ReLU + residual --------------------------------------------
__global__ __launch_bounds__(256) void hg14_final(const float* h2, const float* x,
                                                  const float* gamma, const float* beta,
                                                  const float* bnsum, const float* bnss,
                                                  float* out) {
    int i = blockIdx.x * 256 + threadIdx.x;
    int c = i & 63;
    const float M = (float)(HB * HN);
    float mean = bnsum[c] / M;
    float var  = bnss[c] / M - mean * mean;
    float inv  = rsqrtf(var + 1e-5f);
    float h = gamma[c] * (h2[i] - mean) * inv + beta[c];
    out[i] = fmaxf(h, 0.f) + x[i];
}

extern "C" void kernel_launch(void* const* d_in, const int* in_sizes, int n_in,
                              void* d_out, int out_size, void* d_ws, size_t ws_size,
                              hipStream_t stream) {
    const float* x     = (const float*)d_in[0];
    const float* W     = (const float*)d_in[1];
    const float* bias  = (const float*)d_in[2];
    const float* gamma = (const float*)d_in[3];
    const float* beta  = (const float*)d_in[4];
    float* out = (float*)d_out;
    (void)in_sizes; (void)n_in;

    char* ws = (char*)d_ws;
    size_t off = 0;
    float*        xsq     = (float*)(ws + off);        off += (size_t)HB * HN * 4;
    float*        h1      = (float*)(ws + off);        off += (size_t)HB * HN * HC * 4;
    float*        h2      = (float*)(ws + off);        off += (size_t)HB * HN * HC * 4;
    int*          Dv      = (int*)(ws + off);          off += (size_t)HB * HN * 4;
    int*          indeg   = (int*)(ws + off);          off += (size_t)HB * HN * 4;
    int*          offs    = (int*)(ws + off);          off += (size_t)HB * HN * 4;
    unsigned int* pairs   = (unsigned int*)(ws + off); off += (size_t)NPAIRS * 4;
    float*        bnsum   = (float*)(ws + off);        off += 256;
    float*        bnss    = (float*)(ws + off);        off += 256;
    float*        xT      = (float*)(ws + off);        // z aliases xT (dead after kNN)
    float*        z       = (float*)(ws + off);
    off += (size_t)HB * HE * HC * 4;   // max(xT, z) = z
    size_t base_need = off;
    unsigned int* kcache  = (unsigned int*)(ws + off);
    size_t cache_need = off + (size_t)HB * HN * NSLOT * 64 * 4;   // +84.9 MB

    if (ws_size < base_need) {
        hg14_sentinel<<<(out_size + 255) / 256, 256, 0, stream>>>(out, out_size);
        return;
    }
    const int use_cache = (ws_size >= cache_need) ? 1 : 0;

    const int EDGE_WAVES = NPAIRS + HB * HE2;    // 103312, divisible by 4

    hg14_init<<<(HB * HN + 255) / 256, 256, 0, stream>>>(Dv, indeg, bnsum, bnss);
    hg14_linear<<<HB * HN, 64, 0, stream>>>(x, W, bias, h1, xsq, xT);
    hg22_knn_count<<<HB * (HN / HRPB), 256, 0, stream>>>(xT, xsq, Dv, kcache, use_cache);
    hg15_scan<<<1, 256, 0, stream>>>(Dv, offs);
    if (use_cache)
        hg22_sel<<<HB * (HN / HRPB), 256, 0, stream>>>(kcache, Dv, offs, indeg, pairs);
    else
        hg14_knn_sel_full<<<HB * (HN / HRPB), 256, 0, stream>>>(xT, xsq, Dv, offs, indeg, pairs);
    hg14_scale<<<(HB * HN * HC) / 256, 256, 0, stream>>>(h1, indeg);
    hg14_zero<<<(HB * HN * HC) / 256, 256, 0, stream>>>(z, h2);
    hg14_edge<<<EDGE_WAVES / 4, 256, 0, stream>>>(pairs, Dv, h1, z);
    hg14_gscatter<<<(NPAIRS * 64) / 256, 256, 0, stream>>>(pairs, z, h2);
    hg14_gfinish<<<(HB * HN) / 4, 256, 0, stream>>>(z, indeg, h2);
    hg14_bnstats<<<256, 256, 0, stream>>>(h2, bnsum, bnss);
    hg14_final<<<(HB * HN * HC) / 256, 256, 0, stream>>>(h2, x, gamma, beta, bnsum, bnss, out);
}

// Round 10
// 372.904 us; speedup vs baseline: 1.3692x; 1.3692x over previous
//
#include <hip/hip_runtime.h>

// HGNN layer, v23 — fp32. v22's float8 count (confirmed ~84µs, -7 vs v21)
// + v21's bisection select (proven ~48µs; v22's pop-select was 213µs:
// global-sourced key array can't stay register-resident at VGPR 52, and
// runtime-kk pops expose serial shfl latency at 4.7% occupancy — pops are
// only cheap with LDS-rematerializable keys + high occupancy). Rest = v14
// proven pipeline. B=4, N=2304, C=64.

#define HB    4
#define HN    2304
#define HC    64
#define HK    11             // K_NEIGS + 1
#define HL    48
#define HW    22             // windows per dim
#define HE2   484            // 22*22 local edges
#define HE    (HN + HE2)
#define HRPB  4              // rows per block == waves per block
#define NSLOT 36             // keys per lane (2304/64)
#define NPAIRS (HB * HK * HN)   // sum of Dv == 11*N per batch, exact

__global__ void hg14_sentinel(float* out, int n) {
    int i = blockIdx.x * 256 + threadIdx.x;
    if (i < n) out[i] = 12345.0f;
}

__global__ void hg14_init(int* Dv, int* indeg, float* bnsum, float* bnss) {
    int i = blockIdx.x * 256 + threadIdx.x;
    if (i < HB * HN) { Dv[i] = 0; indeg[i] = 0; }
    if (i < HC) { bnsum[i] = 0.f; bnss[i] = 0.f; }
}

// -------- linear h1 = x W^T + b, xsq, f32 transpose -----------------------
__global__ __launch_bounds__(64) void hg14_linear(const float* x, const float* W,
                                                  const float* bias, float* h1,
                                                  float* xsq, float* xT) {
    int row = blockIdx.x;            // 0..B*N-1
    int t = threadIdx.x;
    __shared__ float xr[HC];
    float v = x[row * HC + t];
    xr[t] = v;
    __syncthreads();
    float sq = v * v;
    #pragma unroll
    for (int o = 32; o > 0; o >>= 1) sq += __shfl_xor(sq, o);
    if (t == 0) xsq[row] = sq;
    int b = row / HN, n = row % HN;
    xT[(b * HC + t) * HN + n] = v;
    float acc = bias[t];
    #pragma unroll 8
    for (int c = 0; c < HC; c++) acc += xr[c] * W[t * HC + c];
    h1[row * HC + t] = acc;
}

// ======== pop machinery (v12-proven): compile-time kk=11 in count only ====
__device__ __forceinline__ unsigned hg14_wave_min_u32(unsigned v) {
    #pragma unroll
    for (int o = 32; o > 0; o >>= 1) {
        unsigned ov = __shfl_xor(v, o);
        v = ov < v ? ov : v;
    }
    return v;
}

#define HG14_INS4(q0, q1, q2, q3, x)                                     \
    {                                                                    \
        unsigned long long x_ = (x), n_;                                 \
        n_ = q0 < x_ ? q0 : x_; x_ = q0 < x_ ? x_ : q0; q0 = n_;         \
        n_ = q1 < x_ ? q1 : x_; x_ = q1 < x_ ? x_ : q1; q1 = n_;         \
        n_ = q2 < x_ ? q2 : x_; x_ = q2 < x_ ? x_ : q2; q2 = n_;         \
        if (x_ < q3) q3 = x_;                                            \
    }

#define HG14_CE(u, v)                                                    \
    { unsigned long long t_ = u < v ? u : v; v = u < v ? v : u; u = t_; }

#define HG14_BUILD()                                                               \
    {                                                                              \
        unsigned long long a0 = CINF, a1 = CINF, a2 = CINF, a3 = CINF;             \
        unsigned long long b0 = CINF, b1 = CINF, b2 = CINF, b3 = CINF;             \
        _Pragma("unroll")                                                          \
        for (int s = 0; s < NSLOT / 2; s++) {                                      \
            unsigned long long pa = ((unsigned long long)key[s] << 12) |           \
                                    (unsigned)((s << 6) | lane);                   \
            unsigned long long pb = ((unsigned long long)key[s + 18] << 12) |      \
                                    (unsigned)(((s + 18) << 6) | lane);            \
            HG14_INS4(a0, a1, a2, a3, pa);                                         \
            HG14_INS4(b0, b1, b2, b3, pb);                                         \
        }                                                                          \
        c0 = a0 < b3 ? a0 : b3; c1 = a1 < b2 ? a1 : b2;                            \
        c2 = a2 < b1 ? a2 : b1; c3 = a3 < b0 ? a3 : b0;                            \
        HG14_CE(c0, c2); HG14_CE(c1, c3); HG14_CE(c0, c1); HG14_CE(c2, c3);        \
    }

#define HG14_EXTRACT(kk, EMIT)                                                     \
    {                                                                              \
        for (int j = 0; j < (kk); j++) {                                           \
            unsigned hk = (unsigned)(c0 >> 12);                                    \
            unsigned mk = hg14_wave_min_u32(hk);                                   \
            unsigned long long bal = __ballot(hk == mk);                           \
            bool iswin;                                                            \
            if (__popcll(bal) == 1) {                                              \
                iswin = (hk == mk);                                                \
            } else {                                                               \
                unsigned mc = (hk == mk) ? (unsigned)(c0 & 0xFFFu) : 0xFFFFFFFFu;  \
                unsigned mm = hg14_wave_min_u32(mc);                               \
                iswin = (mc == mm);                                                \
            }                                                                      \
            if (iswin) {                                                           \
                int bi = (int)(c0 & 0xFFFu);                                       \
                EMIT;                                                              \
                unsigned long long popped = c0;                                    \
                c0 = c1; c1 = c2; c2 = c3; c3 = CINF;                              \
                if (c0 == CINF) {                                                  \
                    _Pragma("unroll")                                              \
                    for (int s = 0; s < NSLOT; s++) {                              \
                        unsigned long long pk =                                    \
                            ((unsigned long long)key[s] << 12) |                   \
                            (unsigned)((s << 6) | lane);                           \
                        if (pk > popped) HG14_INS4(c0, c1, c2, c3, pk);            \
                    }                                                              \
                }                                                                  \
            }                                                                      \
        }                                                                          \
    }

// ======== bisection machinery (v13-proven): select path ===================
__device__ __forceinline__ void hg14_kth(const unsigned (&key)[NSLOT], int kk,
                                         unsigned& T, int& cntLess, int& take) {
    unsigned andv = 0xFFFFFFFFu, orv = 0u;
    #pragma unroll
    for (int s = 0; s < NSLOT; s++) { andv &= key[s]; orv |= key[s]; }
    #pragma unroll
    for (int o = 32; o > 0; o >>= 1) {
        andv &= (unsigned)__shfl_xor((int)andv, o);
        orv  |= (unsigned)__shfl_xor((int)orv, o);
    }
    unsigned diff = andv ^ orv;
    if (diff == 0u) { T = andv; cntLess = 0; take = kk; return; }
    int tstart = 31 - __builtin_clz(diff);
    unsigned lowmask = (tstart == 31) ? 0xFFFFFFFFu : ((1u << (tstart + 1)) - 1u);
    unsigned pref = andv & ~lowmask;
    int r = kk;
    for (int t = tstart; t >= 0; t--) {
        unsigned pt = pref >> t;
        int c = 0;
        #pragma unroll
        for (int s = 0; s < NSLOT; s++) c += ((key[s] >> t) == pt) ? 1 : 0;
        #pragma unroll
        for (int o = 32; o > 0; o >>= 1) c += __shfl_xor(c, o);
        if (r > c) { r -= c; pref |= (1u << t); }
    }
    T = pref; cntLess = kk - r; take = r;
}

__device__ __forceinline__ void hg14_scan64(int v, int lane, int& excl, int& total) {
    int inc = v;
    #pragma unroll
    for (int o = 1; o < 64; o <<= 1) {
        int u = __shfl_up(inc, o);
        if (lane >= o) inc += u;
    }
    excl = inc - v;
    total = __shfl(inc, 63);
}

// -------- kNN count v22: float8 m-vectorization + key store + pop top-11 --
#define HG22_R(qa, qb, s)                                                \
    qa.x += (s) * u.x; qa.y += (s) * u.y; qa.z += (s) * u.z; qa.w += (s) * u.w; \
    qb.x += (s) * v.x; qb.y += (s) * v.y; qb.z += (s) * v.z; qb.w += (s) * v.w;

#define HG22_ST(row, qa, qb, mm)                                               \
    *reinterpret_cast<float4*>(&d[row][(mm)]) =                                \
        make_float4(xs[row] + s0.x - 2.f * qa.x, xs[row] + s0.y - 2.f * qa.y,  \
                    xs[row] + s0.z - 2.f * qa.z, xs[row] + s0.w - 2.f * qa.w); \
    *reinterpret_cast<float4*>(&d[row][(mm) + 4]) =                            \
        make_float4(xs[row] + s1.x - 2.f * qb.x, xs[row] + s1.y - 2.f * qb.y,  \
                    xs[row] + s1.z - 2.f * qb.z, xs[row] + s1.w - 2.f * qb.w);

#define HG22_DIST8(mm)                                                         \
    {                                                                          \
        float4 q0a = {0.f,0.f,0.f,0.f}, q0b = {0.f,0.f,0.f,0.f};               \
        float4 q1a = {0.f,0.f,0.f,0.f}, q1b = {0.f,0.f,0.f,0.f};               \
        float4 q2a = {0.f,0.f,0.f,0.f}, q2b = {0.f,0.f,0.f,0.f};               \
        float4 q3a = {0.f,0.f,0.f,0.f}, q3b = {0.f,0.f,0.f,0.f};               \
        _Pragma("unroll 8")                                                    \
        for (int c = 0; c < HC; c++) {                                         \
            float4 xq = *reinterpret_cast<const float4*>(&xrt[c][0]);          \
            const float* bp = &xT[(b * HC + c) * HN + (mm)];                   \
            float4 u = *reinterpret_cast<const float4*>(bp);                   \
            float4 v = *reinterpret_cast<const float4*>(bp + 4);               \
            HG22_R(q0a, q0b, xq.x); HG22_R(q1a, q1b, xq.y);                    \
            HG22_R(q2a, q2b, xq.z); HG22_R(q3a, q3b, xq.w);                    \
        }                                                                      \
        float4 s0 = *reinterpret_cast<const float4*>(&xsq[b * HN + (mm)]);     \
        float4 s1 = *reinterpret_cast<const float4*>(&xsq[b * HN + (mm) + 4]); \
        HG22_ST(0, q0a, q0b, (mm)); HG22_ST(1, q1a, q1b, (mm));                \
        HG22_ST(2, q2a, q2b, (mm)); HG22_ST(3, q3a, q3b, (mm));                \
    }

__global__ __launch_bounds__(256) void hg22_knn_count(const float* xT, const float* xsq,
                                                      int* Dv, unsigned int* kcache,
                                                      int storekeys) {
    __shared__ float d[HRPB][HN];                // 36 KB
    __shared__ __align__(16) float xrt[HC][HRPB];// [c][row] -> b128 uniform reads
    const int t = threadIdx.x;
    const int b = blockIdx.x / (HN / HRPB);
    const int n0 = (blockIdx.x % (HN / HRPB)) * HRPB;
    const int r = t >> 6;
    const int lane = t & 63;
    xrt[lane][r] = xT[(b * HC + lane) * HN + n0 + r];
    __syncthreads();
    float xs[HRPB];
    #pragma unroll
    for (int q = 0; q < HRPB; q++) xs[q] = xsq[b * HN + n0 + q];

    // per-(p,m) accumulation stays c-ascending scalar fp: bit-identical
    HG22_DIST8(8 * t);                           // m = 0..2047
    if (t < 32) HG22_DIST8(2048 + 8 * t);        // tail m = 2048..2303
    __syncthreads();

    const int p = n0 + r;
    const unsigned long long CINF = ~0ull;
    unsigned int key[NSLOT];
    unsigned long long c0, c1, c2, c3;
    const int rowbase = (b * HN + p) * NSLOT;
    #pragma unroll
    for (int s = 0; s < NSLOT; s++) {
        float f = d[r][(s << 6) | lane];
        unsigned int ub = __float_as_uint(f);
        unsigned int k = ub ^ (((unsigned int)(((int)ub) >> 31)) | 0x80000000u);
        key[s] = k;
        if (storekeys) kcache[(rowbase + s) * 64 + lane] = k;
    }
    HG14_BUILD();
    HG14_EXTRACT(HK, atomicAdd(&Dv[b * HN + bi], 1));
}

// -------- exclusive scan of Dv (9216 = 256*36) into offs, wave-parallel ---
__global__ __launch_bounds__(256) void hg15_scan(const int* Dv, int* offs) {
    __shared__ int wsum[4];
    int t = threadIdx.x;
    int lane = t & 63, w = t >> 6;
    int base = t * 36;
    int s = 0;
    for (int i = 0; i < 36; i++) s += max(Dv[base + i], 1);
    int inc = s;
    #pragma unroll
    for (int o = 1; o < 64; o <<= 1) {
        int u = __shfl_up(inc, o);
        if (lane >= o) inc += u;
    }
    if (lane == 63) wsum[w] = inc;
    __syncthreads();
    int woff = 0;
    for (int i = 0; i < w; i++) woff += wsum[i];
    int acc = woff + inc - s;                    // exclusive prefix for this thread
    for (int i = 0; i < 36; i++) { offs[base + i] = acc; acc += max(Dv[base + i], 1); }
}

// -------- select body: threshold + parallel emission (v13-proven) ---------
__device__ __forceinline__ void hg14_select_emit(const unsigned (&key)[NSLOT],
                                                 int b, int p, int lane, int kk, int base,
                                                 int* indeg, unsigned int* pairs) {
    unsigned T; int cntLess, take;
    hg14_kth(key, kk, T, cntLess, take);
    int cl = 0;
    #pragma unroll
    for (int s = 0; s < NSLOT; s++) cl += (key[s] < T) ? 1 : 0;
    int off, tot;
    hg14_scan64(cl, lane, off, tot);
    int w = 0;
    #pragma unroll
    for (int s = 0; s < NSLOT; s++) {
        if (key[s] < T) {
            int m = (s << 6) | lane;
            atomicAdd(&indeg[b * HN + m], 1);
            pairs[base + off + w] =
                ((unsigned)b << 24) | ((unsigned)p << 12) | (unsigned)m;
            w++;
        }
    }
    int lastm = -1;
    for (int t2 = 0; t2 < take; t2++) {
        int mc = 0x7FFFFFFF;
        #pragma unroll
        for (int s = 0; s < NSLOT; s++) {
            int m = (s << 6) | lane;
            if (key[s] == T && m > lastm && m < mc) mc = m;
        }
        int mmin = mc;
        #pragma unroll
        for (int o = 32; o > 0; o >>= 1) {
            int ov = __shfl_xor(mmin, o);
            mmin = ov < mmin ? ov : mmin;
        }
        if (mc == mmin) {
            atomicAdd(&indeg[b * HN + mmin], 1);
            pairs[base + cntLess + t2] =
                ((unsigned)b << 24) | ((unsigned)p << 12) | (unsigned)mmin;
        }
        lastm = mmin;
    }
}

// -------- kNN select, cached keys (v21-proven) ----------------------------
__global__ __launch_bounds__(256) void hg14_knn_sel_cached(const unsigned int* kcache,
                                                           const int* Dv, const int* offs,
                                                           int* indeg, unsigned int* pairs) {
    const int t = threadIdx.x;
    const int lane = t & 63;
    const int gw = blockIdx.x * HRPB + (t >> 6);   // global row 0..B*N-1
    const int b = gw / HN, p = gw % HN;
    unsigned int key[NSLOT];
    const int rowbase = gw * NSLOT;
    #pragma unroll
    for (int s = 0; s < NSLOT; s++) key[s] = kcache[(rowbase + s) * 64 + lane];
    hg14_select_emit(key, b, p, lane, max(Dv[gw], 1), offs[gw], indeg, pairs);
}

// -------- kNN select, full recompute (fallback, no kcache ws) -------------
__global__ __launch_bounds__(256) void hg14_knn_sel_full(const float* xT, const float* xsq,
                                                         const int* Dv, const int* offs,
                                                         int* indeg, unsigned int* pairs) {
    __shared__ float d[HRPB][HN];
    __shared__ float xr[HRPB][HC];
    const int t = threadIdx.x;
    const int b = blockIdx.x / (HN / HRPB);
    const int n0 = (blockIdx.x % (HN / HRPB)) * HRPB;
    const int r = t >> 6;
    const int lane = t & 63;
    xr[r][lane] = xT[(b * HC + lane) * HN + n0 + r];
    __syncthreads();
    float xs[HRPB];
    #pragma unroll
    for (int q = 0; q < HRPB; q++) xs[q] = xsq[b * HN + n0 + q];
    for (int m = t; m < HN; m += 256) {
        float dot0 = 0.f, dot1 = 0.f, dot2 = 0.f, dot3 = 0.f;
        #pragma unroll 8
        for (int c = 0; c < HC; c++) {
            float xv = xT[(b * HC + c) * HN + m];
            dot0 += xr[0][c] * xv;
            dot1 += xr[1][c] * xv;
            dot2 += xr[2][c] * xv;
            dot3 += xr[3][c] * xv;
        }
        float xsm = xsq[b * HN + m];
        d[0][m] = xs[0] + xsm - 2.f * dot0;
        d[1][m] = xs[1] + xsm - 2.f * dot1;
        d[2][m] = xs[2] + xsm - 2.f * dot2;
        d[3][m] = xs[3] + xsm - 2.f * dot3;
    }
    __syncthreads();
    const int p = n0 + r;
    unsigned int key[NSLOT];
    #pragma unroll
    for (int s = 0; s < NSLOT; s++) {
        float f = d[r][(s << 6) | lane];
        unsigned int ub = __float_as_uint(f);
        key[s] = ub ^ (((unsigned int)(((int)ub) >> 31)) | 0x80000000u);
    }
    const int gw = b * HN + p;
    hg14_select_emit(key, b, p, lane, max(Dv[gw], 1), offs[gw], indeg, pairs);
}

__device__ __forceinline__ int hg14_lo(int rc) { return max(0, (rc - 3) / 2); }
__device__ __forceinline__ int hg14_hi(int rc) { return min(HW - 1, rc / 2); }

// -------- y = Dv^-1/2 * h1 (in place) -------------------------------------
__global__ __launch_bounds__(256) void hg14_scale(float* h1, const int* indeg) {
    int i = blockIdx.x * 256 + threadIdx.x;
    int node = i >> 6;
    int n = node % HN;
    int r = n / HL, c = n % HL;
    int cover = max(0, hg14_hi(r) - hg14_lo(r) + 1) * max(0, hg14_hi(c) - hg14_lo(c) + 1);
    int dvn = max(indeg[node] + cover, 1);
    h1[i] *= rsqrtf((float)dvn);
}

// -------- zero z (kNN-edge part) and h2 -----------------------------------
__global__ void hg14_zero(float* z, float* h2) {
    int i = blockIdx.x * 256 + threadIdx.x;      // over B*N*C
    int b = i / (HN * HC), rem = i % (HN * HC);
    z[b * HE * HC + rem] = 0.f;
    h2[i] = 0.f;
}

// -------- fused edge kernel: kNN scatter + window means -------------------
__global__ __launch_bounds__(256) void hg14_edge(const unsigned int* pairs, const int* Dv,
                                                 const float* y, float* z) {
    int wv = (blockIdx.x * 256 + threadIdx.x) >> 6;
    int lane = threadIdx.x & 63;
    if (wv < NPAIRS) {
        unsigned int pk = pairs[wv];
        int b = pk >> 24;
        if (b >= HB) return;                     // defensive (poison)
        int p = (pk >> 12) & 0xFFF, m = pk & 0xFFF;
        float invde = 1.f / (float)max(Dv[b * HN + p], 1);
        atomicAdd(&z[(b * HE + p) * HC + lane], y[(b * HN + m) * HC + lane] * invde);
    } else {
        int w2 = wv - NPAIRS;
        if (w2 >= HB * HE2) return;
        int b = w2 / HE2, w = w2 % HE2;
        int wr = w / HW, wc = w % HW;
        float acc = 0.f;
        #pragma unroll
        for (int i = 0; i < 5; i++)
            #pragma unroll
            for (int j = 0; j < 5; j++)
                acc += y[(b * HN + (wr * 2 + i) * HL + wc * 2 + j) * HC + lane];
        z[(b * HE + HN + w) * HC + lane] = acc * (1.f / 25.f);
    }
}

// -------- h2[m] += z[p] over the pair list (atomic) -----------------------
__global__ __launch_bounds__(256) void hg14_gscatter(const unsigned int* pairs,
                                                     const float* z, float* h2) {
    int idx = (blockIdx.x * 256 + threadIdx.x) >> 6;
    int lane = threadIdx.x & 63;
    if (idx >= NPAIRS) return;
    unsigned int pk = pairs[idx];
    int b = pk >> 24;
    if (b >= HB) return;                         // defensive (poison)
    int p = (pk >> 12) & 0xFFF, m = pk & 0xFFF;
    atomicAdd(&h2[(b * HN + m) * HC + lane], z[(b * HE + p) * HC + lane]);
}

// -------- add window contributions + final Dv^-1/2 scale ------------------
__global__ __launch_bounds__(256) void hg14_gfinish(const float* z, const int* indeg, float* h2) {
    int wave = (blockIdx.x * 256 + threadIdx.x) >> 6;  // one wave per (b, node)
    int lane = threadIdx.x & 63;
    int b = wave / HN, n = wave % HN;
    int g = b * HN + n;
    float acc = h2[g * HC + lane];
    int r = n / HL, c = n % HL;
    int rlo = hg14_lo(r), rhi = hg14_hi(r), clo = hg14_lo(c), chi = hg14_hi(c);
    for (int wr = rlo; wr <= rhi; wr++)
        for (int wc = clo; wc <= chi; wc++)
            acc += z[(b * HE + HN + wr * HW + wc) * HC + lane];
    int dvn = max(indeg[g] + max(0, rhi - rlo + 1) * max(0, chi - clo + 1), 1);
    h2[g * HC + lane] = acc * rsqrtf((float)dvn);
}

// -------- BN stats --------------------------------------------------------
__global__ __launch_bounds__(256) void hg14_bnstats(const float* h2, float* bnsum, float* bnss) {
    int t = threadIdx.x;
    int c = t & 63, rg = t >> 6;
    int row0 = blockIdx.x * 36;      // 256 blocks * 36 rows = 9216
    float s = 0.f, ss = 0.f;
    for (int r = rg; r < 36; r += 4) {
        float v = h2[(row0 + r) * HC + c];
        s += v; ss += v * v;
    }
    __shared__ float ls[256], lss[256];
    ls[t] = s; lss[t] = ss;
    __syncthreads();
    if (t < 64) {
        s  = ls[t]  + ls[t + 64]  + ls[t + 128]  + ls[t + 192];
        ss = lss[t] + lss[t + 64] + lss[t + 128] + lss[t + 192];
        atomicAdd(&bnsum[t], s);
        atomicAdd(&bnss[t], ss);
    }
}

// -------- BN + ReLU + residual --------------------------------------------
__global__ __launch_bounds__(256) void hg14_final(const float* h2, const float* x,
                                                  const float* gamma, const float* beta,
                                                  const float* bnsum, const float* bnss,
                                                  float* out) {
    int i = blockIdx.x * 256 + threadIdx.x;
    int c = i & 63;
    const float M = (float)(HB * HN);
    float mean = bnsum[c] / M;
    float var  = bnss[c] / M - mean * mean;
    float inv  = rsqrtf(var + 1e-5f);
    float h = gamma[c] * (h2[i] - mean) * inv + beta[c];
    out[i] = fmaxf(h, 0.f) + x[i];
}

extern "C" void kernel_launch(void* const* d_in, const int* in_sizes, int n_in,
                              void* d_out, int out_size, void* d_ws, size_t ws_size,
                              hipStream_t stream) {
    const float* x     = (const float*)d_in[0];
    const float* W     = (const float*)d_in[1];
    const float* bias  = (const float*)d_in[2];
    const float* gamma = (const float*)d_in[3];
    const float* beta  = (const float*)d_in[4];
    float* out = (float*)d_out;
    (void)in_sizes; (void)n_in;

    char* ws = (char*)d_ws;
    size_t off = 0;
    float*        xsq     = (float*)(ws + off);        off += (size_t)HB * HN * 4;
    float*        h1      = (float*)(ws + off);        off += (size_t)HB * HN * HC * 4;
    float*        h2      = (float*)(ws + off);        off += (size_t)HB * HN * HC * 4;
    int*          Dv      = (int*)(ws + off);          off += (size_t)HB * HN * 4;
    int*          indeg   = (int*)(ws + off);          off += (size_t)HB * HN * 4;
    int*          offs    = (int*)(ws + off);          off += (size_t)HB * HN * 4;
    unsigned int* pairs   = (unsigned int*)(ws + off); off += (size_t)NPAIRS * 4;
    float*        bnsum   = (float*)(ws + off);        off += 256;
    float*        bnss    = (float*)(ws + off);        off += 256;
    float*        xT      = (float*)(ws + off);        // z aliases xT (dead after kNN)
    float*        z       = (float*)(ws + off);
    off += (size_t)HB * HE * HC * 4;   // max(xT, z) = z
    size_t base_need = off;
    unsigned int* kcache  = (unsigned int*)(ws + off);
    size_t cache_need = off + (size_t)HB * HN * NSLOT * 64 * 4;   // +84.9 MB

    if (ws_size < base_need) {
        hg14_sentinel<<<(out_size + 255) / 256, 256, 0, stream>>>(out, out_size);
        return;
    }
    const int use_cache = (ws_size >= cache_need) ? 1 : 0;

    const int EDGE_WAVES = NPAIRS + HB * HE2;    // 103312, divisible by 4

    hg14_init<<<(HB * HN + 255) / 256, 256, 0, stream>>>(Dv, indeg, bnsum, bnss);
    hg14_linear<<<HB * HN, 64, 0, stream>>>(x, W, bias, h1, xsq, xT);
    hg22_knn_count<<<HB * (HN / HRPB), 256, 0, stream>>>(xT, xsq, Dv, kcache, use_cache);
    hg15_scan<<<1, 256, 0, stream>>>(Dv, offs);
    if (use_cache)
        hg14_knn_sel_cached<<<HB * (HN / HRPB), 256, 0, stream>>>(kcache, Dv, offs, indeg, pairs);
    else
        hg14_knn_sel_full<<<HB * (HN / HRPB), 256, 0, stream>>>(xT, xsq, Dv, offs, indeg, pairs);
    hg14_scale<<<(HB * HN * HC) / 256, 256, 0, stream>>>(h1, indeg);
    hg14_zero<<<(HB * HN * HC) / 256, 256, 0, stream>>>(z, h2);
    hg14_edge<<<EDGE_WAVES / 4, 256, 0, stream>>>(pairs, Dv, h1, z);
    hg14_gscatter<<<(NPAIRS * 64) / 256, 256, 0, stream>>>(pairs, z, h2);
    hg14_gfinish<<<(HB * HN) / 4, 256, 0, stream>>>(z, indeg, h2);
    hg14_bnstats<<<256, 256, 0, stream>>>(h2, bnsum, bnss);
    hg14_final<<<(HB * HN * HC) / 256, 256, 0, stream>>>(h2, x, gamma, beta, bnsum, bnss, out);
}

// Round 12
// 348.626 us; speedup vs baseline: 1.4645x; 1.0696x over previous
//
#include <hip/hip_runtime.h>

// HGNN layer, v24b — fp32. v21 pipeline (351.6µs best) with count rebuilt as
// SPLIT-m float8: each thread owns m=4t and m=4t+1024 (two float4 chunks).
// Per c-iter: 1 LDS b128 + 2x16B global loads (base + offset:4096) + 32 FMA
// — float8's load density WITHOUT v22's 32B-stride ds_write_b128 bank
// conflicts (v23 measured 13x conflict blowup, 112µs; float4-stride stores
// are the proven benign pattern). Accumulation per (p,m) stays c-ascending
// scalar -> bit-identical keys. v24b: macro params renamed (v24's `w` param
// collided with the .w member accessor under macro substitution).
// B=4, N=2304, C=64.

#define HB    4
#define HN    2304
#define HC    64
#define HK    11             // K_NEIGS + 1
#define HL    48
#define HW    22             // windows per dim
#define HE2   484            // 22*22 local edges
#define HE    (HN + HE2)
#define HRPB  4              // rows per block == waves per block
#define NSLOT 36             // keys per lane (2304/64)
#define NPAIRS (HB * HK * HN)   // sum of Dv == 11*N per batch, exact

__global__ void hg14_sentinel(float* out, int n) {
    int i = blockIdx.x * 256 + threadIdx.x;
    if (i < n) out[i] = 12345.0f;
}

__global__ void hg14_init(int* Dv, int* indeg, float* bnsum, float* bnss) {
    int i = blockIdx.x * 256 + threadIdx.x;
    if (i < HB * HN) { Dv[i] = 0; indeg[i] = 0; }
    if (i < HC) { bnsum[i] = 0.f; bnss[i] = 0.f; }
}

// -------- linear h1 = x W^T + b, xsq, f32 transpose -----------------------
__global__ __launch_bounds__(64) void hg14_linear(const float* x, const float* W,
                                                  const float* bias, float* h1,
                                                  float* xsq, float* xT) {
    int row = blockIdx.x;            // 0..B*N-1
    int t = threadIdx.x;
    __shared__ float xr[HC];
    float v = x[row * HC + t];
    xr[t] = v;
    __syncthreads();
    float sq = v * v;
    #pragma unroll
    for (int o = 32; o > 0; o >>= 1) sq += __shfl_xor(sq, o);
    if (t == 0) xsq[row] = sq;
    int b = row / HN, n = row % HN;
    xT[(b * HC + t) * HN + n] = v;
    float acc = bias[t];
    #pragma unroll 8
    for (int c = 0; c < HC; c++) acc += xr[c] * W[t * HC + c];
    h1[row * HC + t] = acc;
}

// ======== pop machinery (v12-proven): compile-time kk=11 in count only ====
__device__ __forceinline__ unsigned hg14_wave_min_u32(unsigned v) {
    #pragma unroll
    for (int o = 32; o > 0; o >>= 1) {
        unsigned ov = __shfl_xor(v, o);
        v = ov < v ? ov : v;
    }
    return v;
}

#define HG14_INS4(q0, q1, q2, q3, x)                                     \
    {                                                                    \
        unsigned long long x_ = (x), n_;                                 \
        n_ = q0 < x_ ? q0 : x_; x_ = q0 < x_ ? x_ : q0; q0 = n_;         \
        n_ = q1 < x_ ? q1 : x_; x_ = q1 < x_ ? x_ : q1; q1 = n_;         \
        n_ = q2 < x_ ? q2 : x_; x_ = q2 < x_ ? x_ : q2; q2 = n_;         \
        if (x_ < q3) q3 = x_;                                            \
    }

#define HG14_CE(u, v)                                                    \
    { unsigned long long t_ = u < v ? u : v; v = u < v ? v : u; u = t_; }

#define HG14_BUILD()                                                               \
    {                                                                              \
        unsigned long long a0 = CINF, a1 = CINF, a2 = CINF, a3 = CINF;             \
        unsigned long long b0 = CINF, b1 = CINF, b2 = CINF, b3 = CINF;             \
        _Pragma("unroll")                                                          \
        for (int s = 0; s < NSLOT / 2; s++) {                                      \
            unsigned long long pa = ((unsigned long long)key[s] << 12) |           \
                                    (unsigned)((s << 6) | lane);                   \
            unsigned long long pb = ((unsigned long long)key[s + 18] << 12) |      \
                                    (unsigned)(((s + 18) << 6) | lane);            \
            HG14_INS4(a0, a1, a2, a3, pa);                                         \
            HG14_INS4(b0, b1, b2, b3, pb);                                         \
        }                                                                          \
        c0 = a0 < b3 ? a0 : b3; c1 = a1 < b2 ? a1 : b2;                            \
        c2 = a2 < b1 ? a2 : b1; c3 = a3 < b0 ? a3 : b0;                            \
        HG14_CE(c0, c2); HG14_CE(c1, c3); HG14_CE(c0, c1); HG14_CE(c2, c3);        \
    }

#define HG14_EXTRACT(kk, EMIT)                                                     \
    {                                                                              \
        for (int j = 0; j < (kk); j++) {                                           \
            unsigned hk = (unsigned)(c0 >> 12);                                    \
            unsigned mk = hg14_wave_min_u32(hk);                                   \
            unsigned long long bal = __ballot(hk == mk);                           \
            bool iswin;                                                            \
            if (__popcll(bal) == 1) {                                              \
                iswin = (hk == mk);                                                \
            } else {                                                               \
                unsigned mc = (hk == mk) ? (unsigned)(c0 & 0xFFFu) : 0xFFFFFFFFu;  \
                unsigned mm = hg14_wave_min_u32(mc);                               \
                iswin = (mc == mm);                                                \
            }                                                                      \
            if (iswin) {                                                           \
                int bi = (int)(c0 & 0xFFFu);                                       \
                EMIT;                                                              \
                unsigned long long popped = c0;                                    \
                c0 = c1; c1 = c2; c2 = c3; c3 = CINF;                              \
                if (c0 == CINF) {                                                  \
                    _Pragma("unroll")                                              \
                    for (int s = 0; s < NSLOT; s++) {                              \
                        unsigned long long pk =                                    \
                            ((unsigned long long)key[s] << 12) |                   \
                            (unsigned)((s << 6) | lane);                           \
                        if (pk > popped) HG14_INS4(c0, c1, c2, c3, pk);            \
                    }                                                              \
                }                                                                  \
            }                                                                      \
        }                                                                          \
    }

// ======== bisection machinery (v13-proven): select path ===================
__device__ __forceinline__ void hg14_kth(const unsigned (&key)[NSLOT], int kk,
                                         unsigned& T, int& cntLess, int& take) {
    unsigned andv = 0xFFFFFFFFu, orv = 0u;
    #pragma unroll
    for (int s = 0; s < NSLOT; s++) { andv &= key[s]; orv |= key[s]; }
    #pragma unroll
    for (int o = 32; o > 0; o >>= 1) {
        andv &= (unsigned)__shfl_xor((int)andv, o);
        orv  |= (unsigned)__shfl_xor((int)orv, o);
    }
    unsigned diff = andv ^ orv;
    if (diff == 0u) { T = andv; cntLess = 0; take = kk; return; }
    int tstart = 31 - __builtin_clz(diff);
    unsigned lowmask = (tstart == 31) ? 0xFFFFFFFFu : ((1u << (tstart + 1)) - 1u);
    unsigned pref = andv & ~lowmask;
    int r = kk;
    for (int t = tstart; t >= 0; t--) {
        unsigned pt = pref >> t;
        int c = 0;
        #pragma unroll
        for (int s = 0; s < NSLOT; s++) c += ((key[s] >> t) == pt) ? 1 : 0;
        #pragma unroll
        for (int o = 32; o > 0; o >>= 1) c += __shfl_xor(c, o);
        if (r > c) { r -= c; pref |= (1u << t); }
    }
    T = pref; cntLess = kk - r; take = r;
}

__device__ __forceinline__ void hg14_scan64(int v, int lane, int& excl, int& total) {
    int inc = v;
    #pragma unroll
    for (int o = 1; o < 64; o <<= 1) {
        int u = __shfl_up(inc, o);
        if (lane >= o) inc += u;
    }
    excl = inc - v;
    total = __shfl(inc, 63);
}

// -------- kNN count v24: split-m float8 (two float4 chunks 1024 apart) ----
#define HG24_R4(qq, ss, ww)                                              \
    qq.x += (ss) * ww.x; qq.y += (ss) * ww.y;                            \
    qq.z += (ss) * ww.z; qq.w += (ss) * ww.w;

#define HG24_ST4(row, qq, sv, mm)                                              \
    *reinterpret_cast<float4*>(&d[row][(mm)]) =                                \
        make_float4(xs[row] + sv.x - 2.f * qq.x, xs[row] + sv.y - 2.f * qq.y,  \
                    xs[row] + sv.z - 2.f * qq.z, xs[row] + sv.w - 2.f * qq.w);

__global__ __launch_bounds__(256) void hg24_knn_count(const float* xT, const float* xsq,
                                                      int* Dv, unsigned int* kcache,
                                                      int storekeys) {
    __shared__ float d[HRPB][HN];                // 36 KB
    __shared__ __align__(16) float xrt[HC][HRPB];// [c][row] -> b128 uniform reads
    const int t = threadIdx.x;
    const int b = blockIdx.x / (HN / HRPB);
    const int n0 = (blockIdx.x % (HN / HRPB)) * HRPB;
    const int r = t >> 6;
    const int lane = t & 63;
    xrt[lane][r] = xT[(b * HC + lane) * HN + n0 + r];
    __syncthreads();
    float xs[HRPB];
    #pragma unroll
    for (int q = 0; q < HRPB; q++) xs[q] = xsq[b * HN + n0 + q];

    // main: thread t owns m = 4t (chunk A) and m = 4t + 1024 (chunk B).
    // per-(p,m) accumulation stays c-ascending scalar fp: bit-identical.
    {
        const int m = 4 * t;                     // A in [0,1024), B in [1024,2048)
        float4 q0a = {0.f,0.f,0.f,0.f}, q0b = {0.f,0.f,0.f,0.f};
        float4 q1a = {0.f,0.f,0.f,0.f}, q1b = {0.f,0.f,0.f,0.f};
        float4 q2a = {0.f,0.f,0.f,0.f}, q2b = {0.f,0.f,0.f,0.f};
        float4 q3a = {0.f,0.f,0.f,0.f}, q3b = {0.f,0.f,0.f,0.f};
        #pragma unroll 8
        for (int c = 0; c < HC; c++) {
            float4 xq = *reinterpret_cast<const float4*>(&xrt[c][0]);
            const float* bp = &xT[(b * HC + c) * HN + m];
            float4 ua = *reinterpret_cast<const float4*>(bp);
            float4 ub = *reinterpret_cast<const float4*>(bp + 1024);
            HG24_R4(q0a, xq.x, ua); HG24_R4(q0b, xq.x, ub);
            HG24_R4(q1a, xq.y, ua); HG24_R4(q1b, xq.y, ub);
            HG24_R4(q2a, xq.z, ua); HG24_R4(q2b, xq.z, ub);
            HG24_R4(q3a, xq.w, ua); HG24_R4(q3b, xq.w, ub);
        }
        float4 s0 = *reinterpret_cast<const float4*>(&xsq[b * HN + m]);
        float4 s1 = *reinterpret_cast<const float4*>(&xsq[b * HN + m + 1024]);
        HG24_ST4(0, q0a, s0, m); HG24_ST4(0, q0b, s1, m + 1024);
        HG24_ST4(1, q1a, s0, m); HG24_ST4(1, q1b, s1, m + 1024);
        HG24_ST4(2, q2a, s0, m); HG24_ST4(2, q2b, s1, m + 1024);
        HG24_ST4(3, q3a, s0, m); HG24_ST4(3, q3b, s1, m + 1024);
    }
    if (t < 64) {                                // tail: m = 2048 + 4t .. 2303
        const int m = 2048 + 4 * t;
        float4 q0 = {0.f,0.f,0.f,0.f}, q1 = {0.f,0.f,0.f,0.f};
        float4 q2 = {0.f,0.f,0.f,0.f}, q3 = {0.f,0.f,0.f,0.f};
        #pragma unroll 8
        for (int c = 0; c < HC; c++) {
            float4 xq = *reinterpret_cast<const float4*>(&xrt[c][0]);
            float4 ua = *reinterpret_cast<const float4*>(&xT[(b * HC + c) * HN + m]);
            HG24_R4(q0, xq.x, ua); HG24_R4(q1, xq.y, ua);
            HG24_R4(q2, xq.z, ua); HG24_R4(q3, xq.w, ua);
        }
        float4 s0 = *reinterpret_cast<const float4*>(&xsq[b * HN + m]);
        HG24_ST4(0, q0, s0, m); HG24_ST4(1, q1, s0, m);
        HG24_ST4(2, q2, s0, m); HG24_ST4(3, q3, s0, m);
    }
    __syncthreads();

    const int p = n0 + r;
    const unsigned long long CINF = ~0ull;
    unsigned int key[NSLOT];
    unsigned long long c0, c1, c2, c3;
    const int rowbase = (b * HN + p) * NSLOT;
    #pragma unroll
    for (int s = 0; s < NSLOT; s++) {
        float f = d[r][(s << 6) | lane];
        unsigned int ub = __float_as_uint(f);
        unsigned int k = ub ^ (((unsigned int)(((int)ub) >> 31)) | 0x80000000u);
        key[s] = k;
        if (storekeys) kcache[(rowbase + s) * 64 + lane] = k;
    }
    HG14_BUILD();
    HG14_EXTRACT(HK, atomicAdd(&Dv[b * HN + bi], 1));
}

// -------- exclusive scan of Dv (9216 = 256*36) into offs, wave-parallel ---
__global__ __launch_bounds__(256) void hg15_scan(const int* Dv, int* offs) {
    __shared__ int wsum[4];
    int t = threadIdx.x;
    int lane = t & 63, w = t >> 6;
    int base = t * 36;
    int s = 0;
    for (int i = 0; i < 36; i++) s += max(Dv[base + i], 1);
    int inc = s;
    #pragma unroll
    for (int o = 1; o < 64; o <<= 1) {
        int u = __shfl_up(inc, o);
        if (lane >= o) inc += u;
    }
    if (lane == 63) wsum[w] = inc;
    __syncthreads();
    int woff = 0;
    for (int i = 0; i < w; i++) woff += wsum[i];
    int acc = woff + inc - s;                    // exclusive prefix for this thread
    for (int i = 0; i < 36; i++) { offs[base + i] = acc; acc += max(Dv[base + i], 1); }
}

// -------- select body: threshold + parallel emission (v13-proven) ---------
__device__ __forceinline__ void hg14_select_emit(const unsigned (&key)[NSLOT],
                                                 int b, int p, int lane, int kk, int base,
                                                 int* indeg, unsigned int* pairs) {
    unsigned T; int cntLess, take;
    hg14_kth(key, kk, T, cntLess, take);
    int cl = 0;
    #pragma unroll
    for (int s = 0; s < NSLOT; s++) cl += (key[s] < T) ? 1 : 0;
    int off, tot;
    hg14_scan64(cl, lane, off, tot);
    int w = 0;
    #pragma unroll
    for (int s = 0; s < NSLOT; s++) {
        if (key[s] < T) {
            int m = (s << 6) | lane;
            atomicAdd(&indeg[b * HN + m], 1);
            pairs[base + off + w] =
                ((unsigned)b << 24) | ((unsigned)p << 12) | (unsigned)m;
            w++;
        }
    }
    int lastm = -1;
    for (int t2 = 0; t2 < take; t2++) {
        int mc = 0x7FFFFFFF;
        #pragma unroll
        for (int s = 0; s < NSLOT; s++) {
            int m = (s << 6) | lane;
            if (key[s] == T && m > lastm && m < mc) mc = m;
        }
        int mmin = mc;
        #pragma unroll
        for (int o = 32; o > 0; o >>= 1) {
            int ov = __shfl_xor(mmin, o);
            mmin = ov < mmin ? ov : mmin;
        }
        if (mc == mmin) {
            atomicAdd(&indeg[b * HN + mmin], 1);
            pairs[base + cntLess + t2] =
                ((unsigned)b << 24) | ((unsigned)p << 12) | (unsigned)mmin;
        }
        lastm = mmin;
    }
}

// -------- kNN select, cached keys (v21-proven) ----------------------------
__global__ __launch_bounds__(256) void hg14_knn_sel_cached(const unsigned int* kcache,
                                                           const int* Dv, const int* offs,
                                                           int* indeg, unsigned int* pairs) {
    const int t = threadIdx.x;
    const int lane = t & 63;
    const int gw = blockIdx.x * HRPB + (t >> 6);   // global row 0..B*N-1
    const int b = gw / HN, p = gw % HN;
    unsigned int key[NSLOT];
    const int rowbase = gw * NSLOT;
    #pragma unroll
    for (int s = 0; s < NSLOT; s++) key[s] = kcache[(rowbase + s) * 64 + lane];
    hg14_select_emit(key, b, p, lane, max(Dv[gw], 1), offs[gw], indeg, pairs);
}

// -------- kNN select, full recompute (fallback, no kcache ws) -------------
__global__ __launch_bounds__(256) void hg14_knn_sel_full(const float* xT, const float* xsq,
                                                         const int* Dv, const int* offs,
                                                         int* indeg, unsigned int* pairs) {
    __shared__ float d[HRPB][HN];
    __shared__ float xr[HRPB][HC];
    const int t = threadIdx.x;
    const int b = blockIdx.x / (HN / HRPB);
    const int n0 = (blockIdx.x % (HN / HRPB)) * HRPB;
    const int r = t >> 6;
    const int lane = t & 63;
    xr[r][lane] = xT[(b * HC + lane) * HN + n0 + r];
    __syncthreads();
    float xs[HRPB];
    #pragma unroll
    for (int q = 0; q < HRPB; q++) xs[q] = xsq[b * HN + n0 + q];
    for (int m = t; m < HN; m += 256) {
        float dot0 = 0.f, dot1 = 0.f, dot2 = 0.f, dot3 = 0.f;
        #pragma unroll 8
        for (int c = 0; c < HC; c++) {
            float xv = xT[(b * HC + c) * HN + m];
            dot0 += xr[0][c] * xv;
            dot1 += xr[1][c] * xv;
            dot2 += xr[2][c] * xv;
            dot3 += xr[3][c] * xv;
        }
        float xsm = xsq[b * HN + m];
        d[0][m] = xs[0] + xsm - 2.f * dot0;
        d[1][m] = xs[1] + xsm - 2.f * dot1;
        d[2][m] = xs[2] + xsm - 2.f * dot2;
        d[3][m] = xs[3] + xsm - 2.f * dot3;
    }
    __syncthreads();
    const int p = n0 + r;
    unsigned int key[NSLOT];
    #pragma unroll
    for (int s = 0; s < NSLOT; s++) {
        float f = d[r][(s << 6) | lane];
        unsigned int ub = __float_as_uint(f);
        key[s] = ub ^ (((unsigned int)(((int)ub) >> 31)) | 0x80000000u);
    }
    const int gw = b * HN + p;
    hg14_select_emit(key, b, p, lane, max(Dv[gw], 1), offs[gw], indeg, pairs);
}

__device__ __forceinline__ int hg14_lo(int rc) { return max(0, (rc - 3) / 2); }
__device__ __forceinline__ int hg14_hi(int rc) { return min(HW - 1, rc / 2); }

// -------- y = Dv^-1/2 * h1 (in place) -------------------------------------
__global__ __launch_bounds__(256) void hg14_scale(float* h1, const int* indeg) {
    int i = blockIdx.x * 256 + threadIdx.x;
    int node = i >> 6;
    int n = node % HN;
    int r = n / HL, c = n % HL;
    int cover = max(0, hg14_hi(r) - hg14_lo(r) + 1) * max(0, hg14_hi(c) - hg14_lo(c) + 1);
    int dvn = max(indeg[node] + cover, 1);
    h1[i] *= rsqrtf((float)dvn);
}

// -------- zero z (kNN-edge part) and h2 -----------------------------------
__global__ void hg14_zero(float* z, float* h2) {
    int i = blockIdx.x * 256 + threadIdx.x;      // over B*N*C
    int b = i / (HN * HC), rem = i % (HN * HC);
    z[b * HE * HC + rem] = 0.f;
    h2[i] = 0.f;
}

// -------- fused edge kernel: kNN scatter + window means -------------------
__global__ __launch_bounds__(256) void hg14_edge(const unsigned int* pairs, const int* Dv,
                                                 const float* y, float* z) {
    int wv = (blockIdx.x * 256 + threadIdx.x) >> 6;
    int lane = threadIdx.x & 63;
    if (wv < NPAIRS) {
        unsigned int pk = pairs[wv];
        int b = pk >> 24;
        if (b >= HB) return;                     // defensive (poison)
        int p = (pk >> 12) & 0xFFF, m = pk & 0xFFF;
        float invde = 1.f / (float)max(Dv[b * HN + p], 1);
        atomicAdd(&z[(b * HE + p) * HC + lane], y[(b * HN + m) * HC + lane] * invde);
    } else {
        int w2 = wv - NPAIRS;
        if (w2 >= HB * HE2) return;
        int b = w2 / HE2, w = w2 % HE2;
        int wr = w / HW, wc = w % HW;
        float acc = 0.f;
        #pragma unroll
        for (int i = 0; i < 5; i++)
            #pragma unroll
            for (int j = 0; j < 5; j++)
                acc += y[(b * HN + (wr * 2 + i) * HL + wc * 2 + j) * HC + lane];
        z[(b * HE + HN + w) * HC + lane] = acc * (1.f / 25.f);
    }
}

// -------- h2[m] += z[p] over the pair list (atomic) -----------------------
__global__ __launch_bounds__(256) void hg14_gscatter(const unsigned int* pairs,
                                                     const float* z, float* h2) {
    int idx = (blockIdx.x * 256 + threadIdx.x) >> 6;
    int lane = threadIdx.x & 63;
    if (idx >= NPAIRS) return;
    unsigned int pk = pairs[idx];
    int b = pk >> 24;
    if (b >= HB) return;                         // defensive (poison)
    int p = (pk >> 12) & 0xFFF, m = pk & 0xFFF;
    atomicAdd(&h2[(b * HN + m) * HC + lane], z[(b * HE + p) * HC + lane]);
}

// -------- add window contributions + final Dv^-1/2 scale ------------------
__global__ __launch_bounds__(256) void hg14_gfinish(const float* z, const int* indeg, float* h2) {
    int wave = (blockIdx.x * 256 + threadIdx.x) >> 6;  // one wave per (b, node)
    int lane = threadIdx.x & 63;
    int b = wave / HN, n = wave % HN;
    int g = b * HN + n;
    float acc = h2[g * HC + lane];
    int r = n / HL, c = n % HL;
    int rlo = hg14_lo(r), rhi = hg14_hi(r), clo = hg14_lo(c), chi = hg14_hi(c);
    for (int wr = rlo; wr <= rhi; wr++)
        for (int wc = clo; wc <= chi; wc++)
            acc += z[(b * HE + HN + wr * HW + wc) * HC + lane];
    int dvn = max(indeg[g] + max(0, rhi - rlo + 1) * max(0, chi - clo + 1), 1);
    h2[g * HC + lane] = acc * rsqrtf((float)dvn);
}

// -------- BN stats --------------------------------------------------------
__global__ __launch_bounds__(256) void hg14_bnstats(const float* h2, float* bnsum, float* bnss) {
    int t = threadIdx.x;
    int c = t & 63, rg = t >> 6;
    int row0 = blockIdx.x * 36;      // 256 blocks * 36 rows = 9216
    float s = 0.f, ss = 0.f;
    for (int r = rg; r < 36; r += 4) {
        float v = h2[(row0 + r) * HC + c];
        s += v; ss += v * v;
    }
    __shared__ float ls[256], lss[256];
    ls[t] = s; lss[t] = ss;
    __syncthreads();
    if (t < 64) {
        s  = ls[t]  + ls[t + 64]  + ls[t + 128]  + ls[t + 192];
        ss = lss[t] + lss[t + 64] + lss[t + 128] + lss[t + 192];
        atomicAdd(&bnsum[t], s);
        atomicAdd(&bnss[t], ss);
    }
}

// -------- BN + ReLU + residual --------------------------------------------
__global__ __launch_bounds__(256) void hg14_final(const float* h2, const float* x,
                                                  const float* gamma, const float* beta,
                                                  const float* bnsum, const float* bnss,
                                                  float* out) {
    int i = blockIdx.x * 256 + threadIdx.x;
    int c = i & 63;
    const float M = (float)(HB * HN);
    float mean = bnsum[c] / M;
    float var  = bnss[c] / M - mean * mean;
    float inv  = rsqrtf(var + 1e-5f);
    float h = gamma[c] * (h2[i] - mean) * inv + beta[c];
    out[i] = fmaxf(h, 0.f) + x[i];
}

extern "C" void kernel_launch(void* const* d_in, const int* in_sizes, int n_in,
                              void* d_out, int out_size, void* d_ws, size_t ws_size,
                              hipStream_t stream) {
    const float* x     = (const float*)d_in[0];
    const float* W     = (const float*)d_in[1];
    const float* bias  = (const float*)d_in[2];
    const float* gamma = (const float*)d_in[3];
    const float* beta  = (const float*)d_in[4];
    float* out = (float*)d_out;
    (void)in_sizes; (void)n_in;

    char* ws = (char*)d_ws;
    size_t off = 0;
    float*        xsq     = (float*)(ws + off);        off += (size_t)HB * HN * 4;
    float*        h1      = (float*)(ws + off);        off += (size_t)HB * HN * HC * 4;
    float*        h2      = (float*)(ws + off);        off += (size_t)HB * HN * HC * 4;
    int*          Dv      = (int*)(ws + off);          off += (size_t)HB * HN * 4;
    int*          indeg   = (int*)(ws + off);          off += (size_t)HB * HN * 4;
    int*          offs    = (int*)(ws + off);          off += (size_t)HB * HN * 4;
    unsigned int* pairs   = (unsigned int*)(ws + off); off += (size_t)NPAIRS * 4;
    float*        bnsum   = (float*)(ws + off);        off += 256;
    float*        bnss    = (float*)(ws + off);        off += 256;
    float*        xT      = (float*)(ws + off);        // z aliases xT (dead after kNN)
    float*        z       = (float*)(ws + off);
    off += (size_t)HB * HE * HC * 4;   // max(xT, z) = z
    size_t base_need = off;
    unsigned int* kcache  = (unsigned int*)(ws + off);
    size_t cache_need = off + (size_t)HB * HN * NSLOT * 64 * 4;   // +84.9 MB

    if (ws_size < base_need) {
        hg14_sentinel<<<(out_size + 255) / 256, 256, 0, stream>>>(out, out_size);
        return;
    }
    const int use_cache = (ws_size >= cache_need) ? 1 : 0;

    const int EDGE_WAVES = NPAIRS + HB * HE2;    // 103312, divisible by 4

    hg14_init<<<(HB * HN + 255) / 256, 256, 0, stream>>>(Dv, indeg, bnsum, bnss);
    hg14_linear<<<HB * HN, 64, 0, stream>>>(x, W, bias, h1, xsq, xT);
    hg24_knn_count<<<HB * (HN / HRPB), 256, 0, stream>>>(xT, xsq, Dv, kcache, use_cache);
    hg15_scan<<<1, 256, 0, stream>>>(Dv, offs);
    if (use_cache)
        hg14_knn_sel_cached<<<HB * (HN / HRPB), 256, 0, stream>>>(kcache, Dv, offs, indeg, pairs);
    else
        hg14_knn_sel_full<<<HB * (HN / HRPB), 256, 0, stream>>>(xT, xsq, Dv, offs, indeg, pairs);
    hg14_scale<<<(HB * HN * HC) / 256, 256, 0, stream>>>(h1, indeg);
    hg14_zero<<<(HB * HN * HC) / 256, 256, 0, stream>>>(z, h2);
    hg14_edge<<<EDGE_WAVES / 4, 256, 0, stream>>>(pairs, Dv, h1, z);
    hg14_gscatter<<<(NPAIRS * 64) / 256, 256, 0, stream>>>(pairs, z, h2);
    hg14_gfinish<<<(HB * HN) / 4, 256, 0, stream>>>(z, indeg, h2);
    hg14_bnstats<<<256, 256, 0, stream>>>(h2, bnsum, bnss);
    hg14_final<<<(HB * HN * HC) / 256, 256, 0, stream>>>(h2, x, gamma, beta, bnsum, bnss, out);
}